// Round 15
// baseline (148.993 us; speedup 1.0000x reference)
//
#include <hip/hip_runtime.h>

typedef unsigned short u16;
typedef __bf16 v8bf __attribute__((ext_vector_type(8)));
typedef float f32x4 __attribute__((ext_vector_type(4)));
typedef float f32x16 __attribute__((ext_vector_type(16)));
typedef u16 us8 __attribute__((ext_vector_type(8)));
typedef u16 us4 __attribute__((ext_vector_type(4)));

static __device__ __forceinline__ u16 f2bf(float f) {
  union { __bf16 h; u16 u; } cv;
  cv.h = (__bf16)f;
  return cv.u;
}

static __device__ __forceinline__ void gl_lds16(const u16* g, u16* l) {
  __builtin_amdgcn_global_load_lds(
      (const __attribute__((address_space(1))) unsigned int*)g,
      (__attribute__((address_space(3))) unsigned int*)l, 16, 0, 0);
}

// ---- prep v2 (small): adj->adjC top half (+adjT) [blocks 0..1023], foldW [1024].
//      x is no longer touched here (prop stages it directly). ----
__global__ __launch_bounds__(256)
void prep_k(const float* __restrict__ adj, u16* __restrict__ adjC,
            u16* __restrict__ adjT_bf, const float* __restrict__ W,
            u16* __restrict__ Mb) {
  const int bid = blockIdx.x;
  const int tid = threadIdx.x;
  __shared__ u16 Ls[64][68];
  if (bid < 1024) {
    const int b = bid >> 6;
    const int r0 = ((bid >> 3) & 7) * 64;
    const int c0 = (bid & 7) * 64;
#pragma unroll
    for (int i = 0; i < 4; ++i) {
      const int idx = tid + 256 * i;
      const int r = idx >> 4;
      const int c4 = (idx & 15) * 4;
      const float4 v = *(const float4*)(adj + ((size_t)(b * 512 + r0 + r) * 512 + c0 + c4));
      us4 o;
      o[0] = f2bf(v.x); o[1] = f2bf(v.y); o[2] = f2bf(v.z); o[3] = f2bf(v.w);
      *(us4*)&Ls[r][c4] = o;
      *(us4*)(adjC + ((size_t)(b * 1024 + r0 + r) * 512 + c0 + c4)) = o;
    }
    __syncthreads();
#pragma unroll
    for (int i = 0; i < 2; ++i) {
      const int idx = tid + 256 * i;
      const int c = idx >> 3;
      const int r8 = (idx & 7) * 8;
      us8 o;
#pragma unroll
      for (int j = 0; j < 8; ++j) o[j] = Ls[r8 + j][c];
      *(us8*)(adjT_bf + ((size_t)(b * 512 + c0 + c) * 512 + r0 + r8)) = o;
    }
  } else {
    for (int i = tid; i < 64 * 96; i += 256) {
      const int cc = i % 96;
      const int r = cc % 3;
      const float w = W[i];
      const float m = (r == 0) ? (w - W[i + 2]) : w;
      Mb[i] = f2bf(m);
    }
  }
}

// ---- adjC lower half = 2 * adj[b] @ adj[b] (unchanged) ----
__global__ __launch_bounds__(256)
void gemm_sq(const u16* __restrict__ adjC_in, const u16* __restrict__ BT,
             u16* __restrict__ adjC) {
  const int b = blockIdx.z;
  const int row0 = blockIdx.y * 128;
  const int col0 = blockIdx.x * 128;
  const u16* Ab = adjC_in + (size_t)b * 1024 * 512;
  const u16* BTb = BT + (size_t)b * 512 * 512;

  __shared__ u16 smem[16384];
  u16* As = smem;
  u16* Bs = smem + 8192;

  const int tid = threadIdx.x;
  const int lane = tid & 63;
  const int w = tid >> 6;
  const int wm = (w >> 1) * 64;
  const int wn = (w & 1) * 64;
  const int l16 = lane & 15;
  const int kg = lane >> 4;

  f32x4 acc[4][4];
#pragma unroll
  for (int m = 0; m < 4; ++m)
#pragma unroll
    for (int n = 0; n < 4; ++n) acc[m][n] = (f32x4){0.f, 0.f, 0.f, 0.f};

  for (int k0 = 0; k0 < 512; k0 += 64) {
    __syncthreads();
#pragma unroll
    for (int i = 0; i < 4; ++i) {
      const int eb = w * 2048 + i * 512;
      const int e = eb + lane * 8;
      const int r = e >> 6;
      const int kk = e & 63;
      gl_lds16(Ab + (size_t)(row0 + r) * 512 + k0 + kk, As + eb);
      gl_lds16(BTb + (size_t)(col0 + r) * 512 + k0 + kk, Bs + eb);
    }
    __syncthreads();
#pragma unroll
    for (int ks = 0; ks < 2; ++ks) {
      v8bf af[4], bfr[4];
#pragma unroll
      for (int m = 0; m < 4; ++m)
        af[m] = *(const v8bf*)(As + (wm + m * 16 + l16) * 64 + ks * 32 + kg * 8);
#pragma unroll
      for (int n = 0; n < 4; ++n)
        bfr[n] = *(const v8bf*)(Bs + (wn + n * 16 + l16) * 64 + ks * 32 + kg * 8);
#pragma unroll
      for (int m = 0; m < 4; ++m)
#pragma unroll
        for (int n = 0; n < 4; ++n)
          acc[m][n] = __builtin_amdgcn_mfma_f32_16x16x32_bf16(af[m], bfr[n], acc[m][n], 0, 0, 0);
    }
  }
  u16* Cb = adjC + (size_t)b * 1024 * 512 + (size_t)512 * 512;
#pragma unroll
  for (int m = 0; m < 4; ++m)
#pragma unroll
    for (int n = 0; n < 4; ++n)
#pragma unroll
      for (int v = 0; v < 4; ++v) {
        const int rr = row0 + wm + m * 16 + kg * 4 + v;
        const int cc = col0 + wn + n * 16 + l16;
        Cb[(size_t)rr * 512 + cc] = f2bf(2.0f * acc[m][n][v]);
      }
}

// ---- propagate v5: A via gl_lds (swizzled source), B staged DIRECTLY from
//      fp32 x with inline bf16 cvt + swizzled ds_write (transpose in flight).
//      Same physical LDS layout as R10/R13 -> read side unchanged. ----
__global__ __launch_bounds__(512)
void prop_k(const u16* __restrict__ AC, const float* __restrict__ X,
            u16* __restrict__ C) {
  const int fid = blockIdx.x + 16 * (blockIdx.y + 4 * blockIdx.z);
  const int wk = (fid & 7) * 128 + (fid >> 3);   // bijective: 1024 % 8 == 0
  const int b = wk >> 6;
  const int row0 = ((wk >> 4) & 3) * 256;
  const int col0 = (wk & 15) * 128;
  const u16* Ab = AC + (size_t)b * 1024 * 512;
  const float* Xb = X + (size_t)b * 512 * 2048;

  __shared__ u16 smem[24576];  // A [256][64] = 32KB, B [128][64] = 16KB
  u16* As = smem;
  u16* Bs = smem + 16384;

  const int tid = threadIdx.x;
  const int lane = tid & 63;
  const int w = tid >> 6;
  const int wm = (w >> 1) * 64;
  const int wn = (w & 1) * 64;
  const int l32 = lane & 31;
  const int hk = lane >> 5;
  const int rsw = (l32 & 7) << 3;
  // B-staging mapping: thread covers column jj, q-octs {qg, qg+4}
  const int jj = tid & 127;
  const int qg = tid >> 7;

  f32x16 acc[2][2];
#pragma unroll
  for (int mi = 0; mi < 2; ++mi)
#pragma unroll
    for (int ni = 0; ni < 2; ++ni)
#pragma unroll
      for (int v = 0; v < 16; ++v) acc[mi][ni][v] = 0.f;

  for (int k0 = 0; k0 < 512; k0 += 64) {
    __syncthreads();
    // A tiles via gl_lds (pre-swizzled source slots, linear LDS dest)
#pragma unroll
    for (int i = 0; i < 4; ++i) {
      const int cb = w * 64 + i * 512;
      const int c = cb + lane;
      const int r = c >> 3;
      const int slot = (c & 7) ^ (r & 7);
      gl_lds16(Ab + (size_t)(row0 + r) * 512 + k0 + slot * 8, As + cb * 8);
    }
    // B tile from x fp32: 8 coalesced scalar loads down q, cvt, one b128
    // ds_write at the swizzled slot (oct ^ (jj&7)) -> read side unchanged.
#pragma unroll
    for (int i = 0; i < 2; ++i) {
      const int oct = qg + i * 4;          // q-oct 0..7
      const float* src = Xb + (size_t)(k0 + oct * 8) * 2048 + col0 + jj;
      float v[8];
#pragma unroll
      for (int u = 0; u < 8; ++u) v[u] = src[(size_t)u * 2048];
      us8 o;
#pragma unroll
      for (int u = 0; u < 8; ++u) o[u] = f2bf(v[u]);
      *(us8*)(Bs + jj * 64 + ((oct ^ (jj & 7)) * 8)) = o;
    }
    __syncthreads();
#pragma unroll
    for (int ks = 0; ks < 4; ++ks) {
      v8bf af[2], bf[2];
#pragma unroll
      for (int mi = 0; mi < 2; ++mi) {
        const int row = wm + mi * 32 + l32;
        af[mi] = *(const v8bf*)(As + row * 64 + ((ks * 16 + hk * 8) ^ rsw));
      }
#pragma unroll
      for (int ni = 0; ni < 2; ++ni) {
        const int row = wn + ni * 32 + l32;
        bf[ni] = *(const v8bf*)(Bs + row * 64 + ((ks * 16 + hk * 8) ^ rsw));
      }
#pragma unroll
      for (int mi = 0; mi < 2; ++mi)
#pragma unroll
        for (int ni = 0; ni < 2; ++ni)
          acc[mi][ni] = __builtin_amdgcn_mfma_f32_32x32x16_bf16(af[mi], bf[ni], acc[mi][ni], 0, 0, 0);
    }
  }

  u16* Cb = C + (size_t)b * 1024 * 2048;
#pragma unroll
  for (int mi = 0; mi < 2; ++mi)
#pragma unroll
    for (int ni = 0; ni < 2; ++ni)
#pragma unroll
      for (int r = 0; r < 16; ++r) {
        const int rr = row0 + wm + mi * 32 + (r & 3) + 8 * (r >> 2) + 4 * hk;
        const int cc = col0 + wn + ni * 32 + l32;
        Cb[(size_t)rr * 2048 + cc] = f2bf(acc[mi][ni][r]);
      }
}

// ---- mix (reverted to R13-proven): per (b,q): out[b,:,q,:] = M @ V + bias. ----
__global__ __launch_bounds__(256)
void mix_mfma(const float* __restrict__ x0, const u16* __restrict__ X1Y2,
              const u16* __restrict__ Mb, const float* __restrict__ bias,
              float* __restrict__ out) {
  const int q = blockIdx.x;
  const int b = blockIdx.y;
  __shared__ u16 Vt[64][104];
  __shared__ u16 Ms[64][104];
  const int tid = threadIdx.x;
  const int lane = tid & 63;
  const int w = tid >> 6;
  const int l16 = lane & 15;
  const int kg = lane >> 4;

#pragma unroll
  for (int i = 0; i < 3; ++i) {
    const int idx = tid + 256 * i;
    const int o = idx / 12;
    const int c8 = (idx % 12) * 8;
    *(uint4*)&Ms[o][c8] = *(const uint4*)(Mb + o * 96 + c8);
  }
  const size_t base0 = ((size_t)b * 512 + q) * 2048;
  const size_t base1 = ((size_t)b * 1024 + q) * 2048;
  const size_t base2 = ((size_t)b * 1024 + 512 + q) * 2048;
#pragma unroll
  for (int i = 0; i < 2; ++i) {
    const int idx = tid + 256 * i;
    const int c = idx >> 4;
    const int l0 = (idx & 15) * 4;
    const float4 v = *(const float4*)(x0 + base0 + c * 64 + l0);
    Vt[l0 + 0][3 * c] = f2bf(v.x);
    Vt[l0 + 1][3 * c] = f2bf(v.y);
    Vt[l0 + 2][3 * c] = f2bf(v.z);
    Vt[l0 + 3][3 * c] = f2bf(v.w);
  }
  {
    const int c = tid >> 3;
    const int l0 = (tid & 7) * 8;
    const us8 v1 = *(const us8*)(X1Y2 + base1 + c * 64 + l0);
    const us8 v2 = *(const us8*)(X1Y2 + base2 + c * 64 + l0);
#pragma unroll
    for (int j = 0; j < 8; ++j) {
      Vt[l0 + j][3 * c + 1] = v1[j];
      Vt[l0 + j][3 * c + 2] = v2[j];
    }
  }
  __syncthreads();

  f32x4 acc[4];
#pragma unroll
  for (int n = 0; n < 4; ++n) acc[n] = (f32x4){0.f, 0.f, 0.f, 0.f};
#pragma unroll
  for (int ks = 0; ks < 3; ++ks) {
    const v8bf a = *(const v8bf*)&Ms[w * 16 + l16][ks * 32 + kg * 8];
#pragma unroll
    for (int n = 0; n < 4; ++n) {
      const v8bf bv = *(const v8bf*)&Vt[n * 16 + l16][ks * 32 + kg * 8];
      acc[n] = __builtin_amdgcn_mfma_f32_16x16x32_bf16(a, bv, acc[n], 0, 0, 0);
    }
  }
#pragma unroll
  for (int n = 0; n < 4; ++n)
#pragma unroll
    for (int v = 0; v < 4; ++v) {
      const int o = w * 16 + kg * 4 + v;
      out[(((size_t)b * 64 + o) * 512 + q) * 64 + n * 16 + l16] = acc[n][v] + bias[o];
    }
}

extern "C" void kernel_launch(void* const* d_in, const int* in_sizes, int n_in,
                              void* d_out, int out_size, void* d_ws, size_t ws_size,
                              hipStream_t stream) {
  const float* x   = (const float*)d_in[0];  // [16,512,32,64]
  const float* adj = (const float*)d_in[1];  // [16,512,512]
  const float* W   = (const float*)d_in[2];  // [64,96]
  const float* bia = (const float*)d_in[3];  // [64]
  float* out = (float*)d_out;                // [16,64,512,64]

  u16* adjC    = (u16*)d_ws;                              // [16][1024][512]
  u16* adjT_bf = adjC    + (size_t)16 * 1024 * 512;       // [16][512][512]
  u16* X1Y2    = adjT_bf + (size_t)16 * 512 * 512;        // [16][1024][2048]
  u16* Mb      = X1Y2    + (size_t)16 * 1024 * 2048;

  hipLaunchKernelGGL(prep_k, dim3(1025), dim3(256), 0, stream,
                     adj, adjC, adjT_bf, W, Mb);
  hipLaunchKernelGGL(gemm_sq, dim3(4, 4, 16), dim3(256), 0, stream,
                     adjC, adjT_bf, adjC);
  hipLaunchKernelGGL(prop_k, dim3(16, 4, 16), dim3(512), 0, stream,
                     adjC, x, X1Y2);
  hipLaunchKernelGGL(mix_mfma, dim3(512, 16), dim3(256), 0, stream,
                     x, X1Y2, Mb, bia, out);
}

// Round 16
// 138.481 us; speedup vs baseline: 1.0759x; 1.0759x over previous
//
#include <hip/hip_runtime.h>

typedef unsigned short u16;
typedef __bf16 v8bf __attribute__((ext_vector_type(8)));
typedef float f32x4 __attribute__((ext_vector_type(4)));
typedef float f32x16 __attribute__((ext_vector_type(16)));
typedef u16 us8 __attribute__((ext_vector_type(8)));
typedef u16 us4 __attribute__((ext_vector_type(4)));

static __device__ __forceinline__ u16 f2bf(float f) {
  union { __bf16 h; u16 u; } cv;
  cv.h = (__bf16)f;
  return cv.u;
}

static __device__ __forceinline__ void gl_lds16(const u16* g, u16* l) {
  __builtin_amdgcn_global_load_lds(
      (const __attribute__((address_space(1))) unsigned int*)g,
      (__attribute__((address_space(3))) unsigned int*)l, 16, 0, 0);
}

// ---- merged prep (R13-proven): adj->adjC top half (+adjT) [blocks 0..1023],
//      x->xT [1024..5119], foldW [5120] ----
__global__ __launch_bounds__(256)
void prep_k(const float* __restrict__ adj, u16* __restrict__ adjC,
            u16* __restrict__ adjT_bf, const float* __restrict__ x,
            u16* __restrict__ xT, const float* __restrict__ W,
            u16* __restrict__ Mb) {
  const int bid = blockIdx.x;
  const int tid = threadIdx.x;
  __shared__ u16 Ls[64][68];
  if (bid < 1024) {
    const int b = bid >> 6;
    const int r0 = ((bid >> 3) & 7) * 64;
    const int c0 = (bid & 7) * 64;
#pragma unroll
    for (int i = 0; i < 4; ++i) {
      const int idx = tid + 256 * i;
      const int r = idx >> 4;
      const int c4 = (idx & 15) * 4;
      const float4 v = *(const float4*)(adj + ((size_t)(b * 512 + r0 + r) * 512 + c0 + c4));
      us4 o;
      o[0] = f2bf(v.x); o[1] = f2bf(v.y); o[2] = f2bf(v.z); o[3] = f2bf(v.w);
      *(us4*)&Ls[r][c4] = o;
      *(us4*)(adjC + ((size_t)(b * 1024 + r0 + r) * 512 + c0 + c4)) = o;
    }
    __syncthreads();
#pragma unroll
    for (int i = 0; i < 2; ++i) {
      const int idx = tid + 256 * i;
      const int c = idx >> 3;
      const int r8 = (idx & 7) * 8;
      us8 o;
#pragma unroll
      for (int j = 0; j < 8; ++j) o[j] = Ls[r8 + j][c];
      *(us8*)(adjT_bf + ((size_t)(b * 512 + c0 + c) * 512 + r0 + r8)) = o;
    }
  } else if (bid < 5120) {
    const int t = bid - 1024;
    const int b = t >> 8;
    const int q0 = ((t >> 5) & 7) * 64;
    const int j0 = (t & 31) * 64;
#pragma unroll
    for (int i = 0; i < 4; ++i) {
      const int idx = tid + 256 * i;
      const int r = idx >> 4;
      const int j4 = (idx & 15) * 4;
      const float4 v = *(const float4*)(x + ((size_t)(b * 512 + q0 + r) * 2048 + j0 + j4));
      us4 o;
      o[0] = f2bf(v.x); o[1] = f2bf(v.y); o[2] = f2bf(v.z); o[3] = f2bf(v.w);
      *(us4*)&Ls[r][j4] = o;
    }
    __syncthreads();
#pragma unroll
    for (int i = 0; i < 2; ++i) {
      const int idx = tid + 256 * i;
      const int jp = idx >> 3;
      const int q8 = (idx & 7) * 8;
      us8 o;
#pragma unroll
      for (int j = 0; j < 8; ++j) o[j] = Ls[q8 + j][jp];
      *(us8*)(xT + ((size_t)(b * 2048 + j0 + jp) * 512 + q0 + q8)) = o;
    }
  } else {
    for (int i = tid; i < 64 * 96; i += 256) {
      const int cc = i % 96;
      const int r = cc % 3;
      const float w = W[i];
      const float m = (r == 0) ? (w - W[i + 2]) : w;
      Mb[i] = f2bf(m);
    }
  }
}

// ---- adjC lower half = 2 * adj[b] @ adj[b] (unchanged) ----
__global__ __launch_bounds__(256)
void gemm_sq(const u16* __restrict__ adjC_in, const u16* __restrict__ BT,
             u16* __restrict__ adjC) {
  const int b = blockIdx.z;
  const int row0 = blockIdx.y * 128;
  const int col0 = blockIdx.x * 128;
  const u16* Ab = adjC_in + (size_t)b * 1024 * 512;
  const u16* BTb = BT + (size_t)b * 512 * 512;

  __shared__ u16 smem[16384];
  u16* As = smem;
  u16* Bs = smem + 8192;

  const int tid = threadIdx.x;
  const int lane = tid & 63;
  const int w = tid >> 6;
  const int wm = (w >> 1) * 64;
  const int wn = (w & 1) * 64;
  const int l16 = lane & 15;
  const int kg = lane >> 4;

  f32x4 acc[4][4];
#pragma unroll
  for (int m = 0; m < 4; ++m)
#pragma unroll
    for (int n = 0; n < 4; ++n) acc[m][n] = (f32x4){0.f, 0.f, 0.f, 0.f};

  for (int k0 = 0; k0 < 512; k0 += 64) {
    __syncthreads();
#pragma unroll
    for (int i = 0; i < 4; ++i) {
      const int eb = w * 2048 + i * 512;
      const int e = eb + lane * 8;
      const int r = e >> 6;
      const int kk = e & 63;
      gl_lds16(Ab + (size_t)(row0 + r) * 512 + k0 + kk, As + eb);
      gl_lds16(BTb + (size_t)(col0 + r) * 512 + k0 + kk, Bs + eb);
    }
    __syncthreads();
#pragma unroll
    for (int ks = 0; ks < 2; ++ks) {
      v8bf af[4], bfr[4];
#pragma unroll
      for (int m = 0; m < 4; ++m)
        af[m] = *(const v8bf*)(As + (wm + m * 16 + l16) * 64 + ks * 32 + kg * 8);
#pragma unroll
      for (int n = 0; n < 4; ++n)
        bfr[n] = *(const v8bf*)(Bs + (wn + n * 16 + l16) * 64 + ks * 32 + kg * 8);
#pragma unroll
      for (int m = 0; m < 4; ++m)
#pragma unroll
        for (int n = 0; n < 4; ++n)
          acc[m][n] = __builtin_amdgcn_mfma_f32_16x16x32_bf16(af[m], bfr[n], acc[m][n], 0, 0, 0);
    }
  }
  u16* Cb = adjC + (size_t)b * 1024 * 512 + (size_t)512 * 512;
#pragma unroll
  for (int m = 0; m < 4; ++m)
#pragma unroll
    for (int n = 0; n < 4; ++n)
#pragma unroll
      for (int v = 0; v < 4; ++v) {
        const int rr = row0 + wm + m * 16 + kg * 4 + v;
        const int cc = col0 + wn + n * 16 + l16;
        Cb[(size_t)rr * 512 + cc] = f2bf(2.0f * acc[m][n][v]);
      }
}

// ---- propagate v6: 128x128 tile, 4 waves, 32x32x16 MFMA, both-sides XOR
//      swizzle (R10 math), 32KB LDS -> 5 blocks/CU, 2048 blocks.
//      X1Y2[b](1024x2048) = adjC[b] @ X[b] (xT k-major). ----
__global__ __launch_bounds__(256)
void prop_k(const u16* __restrict__ AC, const u16* __restrict__ BT,
            u16* __restrict__ C) {
  const int fid = blockIdx.x + 16 * (blockIdx.y + 8 * blockIdx.z);
  const int wk = (fid & 7) * 256 + (fid >> 3);   // bijective: 2048 % 8 == 0
  const int b = wk >> 7;
  const int row0 = ((wk >> 4) & 7) * 128;
  const int col0 = (wk & 15) * 128;
  const u16* Ab = AC + (size_t)b * 1024 * 512;
  const u16* BTb = BT + (size_t)b * 2048 * 512;

  __shared__ u16 smem[16384];  // A [128][64] = 16KB, B [128][64] = 16KB
  u16* As = smem;
  u16* Bs = smem + 8192;

  const int tid = threadIdx.x;
  const int lane = tid & 63;
  const int w = tid >> 6;          // 0..3
  const int wm = (w >> 1) * 64;
  const int wn = (w & 1) * 64;
  const int l32 = lane & 31;
  const int hk = lane >> 5;
  const int rsw = (l32 & 7) << 3;

  f32x16 acc[2][2];
#pragma unroll
  for (int mi = 0; mi < 2; ++mi)
#pragma unroll
    for (int ni = 0; ni < 2; ++ni)
#pragma unroll
      for (int v = 0; v < 16; ++v) acc[mi][ni][v] = 0.f;

  for (int k0 = 0; k0 < 512; k0 += 64) {
    __syncthreads();
    // 1024 chunks per tile; 4 per thread; pre-swizzled source slot
#pragma unroll
    for (int i = 0; i < 4; ++i) {
      const int cb = w * 64 + i * 256;      // wave-uniform chunk base
      const int c = cb + lane;
      const int r = c >> 3;
      const int slot = (c & 7) ^ (r & 7);
      gl_lds16(Ab + (size_t)(row0 + r) * 512 + k0 + slot * 8, As + cb * 8);
      gl_lds16(BTb + (size_t)(col0 + r) * 512 + k0 + slot * 8, Bs + cb * 8);
    }
    __syncthreads();
#pragma unroll
    for (int ks = 0; ks < 4; ++ks) {
      v8bf af[2], bf[2];
#pragma unroll
      for (int mi = 0; mi < 2; ++mi) {
        const int row = wm + mi * 32 + l32;
        af[mi] = *(const v8bf*)(As + row * 64 + ((ks * 16 + hk * 8) ^ rsw));
      }
#pragma unroll
      for (int ni = 0; ni < 2; ++ni) {
        const int row = wn + ni * 32 + l32;
        bf[ni] = *(const v8bf*)(Bs + row * 64 + ((ks * 16 + hk * 8) ^ rsw));
      }
#pragma unroll
      for (int mi = 0; mi < 2; ++mi)
#pragma unroll
        for (int ni = 0; ni < 2; ++ni)
          acc[mi][ni] = __builtin_amdgcn_mfma_f32_32x32x16_bf16(af[mi], bf[ni], acc[mi][ni], 0, 0, 0);
    }
  }

  // C/D 32x32 layout: col = lane&31, row = (r&3)+8*(r>>2)+4*(lane>>5)
  u16* Cb = C + (size_t)b * 1024 * 2048;
#pragma unroll
  for (int mi = 0; mi < 2; ++mi)
#pragma unroll
    for (int ni = 0; ni < 2; ++ni)
#pragma unroll
      for (int r = 0; r < 16; ++r) {
        const int rr = row0 + wm + mi * 32 + (r & 3) + 8 * (r >> 2) + 4 * hk;
        const int cc = col0 + wn + ni * 32 + l32;
        Cb[(size_t)rr * 2048 + cc] = f2bf(acc[mi][ni][r]);
      }
}

// ---- mix (R13-proven, unchanged) ----
__global__ __launch_bounds__(256)
void mix_mfma(const float* __restrict__ x0, const u16* __restrict__ X1Y2,
              const u16* __restrict__ Mb, const float* __restrict__ bias,
              float* __restrict__ out) {
  const int q = blockIdx.x;
  const int b = blockIdx.y;
  __shared__ u16 Vt[64][104];
  __shared__ u16 Ms[64][104];
  const int tid = threadIdx.x;
  const int lane = tid & 63;
  const int w = tid >> 6;
  const int l16 = lane & 15;
  const int kg = lane >> 4;

#pragma unroll
  for (int i = 0; i < 3; ++i) {
    const int idx = tid + 256 * i;
    const int o = idx / 12;
    const int c8 = (idx % 12) * 8;
    *(uint4*)&Ms[o][c8] = *(const uint4*)(Mb + o * 96 + c8);
  }
  const size_t base0 = ((size_t)b * 512 + q) * 2048;
  const size_t base1 = ((size_t)b * 1024 + q) * 2048;
  const size_t base2 = ((size_t)b * 1024 + 512 + q) * 2048;
#pragma unroll
  for (int i = 0; i < 2; ++i) {
    const int idx = tid + 256 * i;
    const int c = idx >> 4;
    const int l0 = (idx & 15) * 4;
    const float4 v = *(const float4*)(x0 + base0 + c * 64 + l0);
    Vt[l0 + 0][3 * c] = f2bf(v.x);
    Vt[l0 + 1][3 * c] = f2bf(v.y);
    Vt[l0 + 2][3 * c] = f2bf(v.z);
    Vt[l0 + 3][3 * c] = f2bf(v.w);
  }
  {
    const int c = tid >> 3;
    const int l0 = (tid & 7) * 8;
    const us8 v1 = *(const us8*)(X1Y2 + base1 + c * 64 + l0);
    const us8 v2 = *(const us8*)(X1Y2 + base2 + c * 64 + l0);
#pragma unroll
    for (int j = 0; j < 8; ++j) {
      Vt[l0 + j][3 * c + 1] = v1[j];
      Vt[l0 + j][3 * c + 2] = v2[j];
    }
  }
  __syncthreads();

  f32x4 acc[4];
#pragma unroll
  for (int n = 0; n < 4; ++n) acc[n] = (f32x4){0.f, 0.f, 0.f, 0.f};
#pragma unroll
  for (int ks = 0; ks < 3; ++ks) {
    const v8bf a = *(const v8bf*)&Ms[w * 16 + l16][ks * 32 + kg * 8];
#pragma unroll
    for (int n = 0; n < 4; ++n) {
      const v8bf bv = *(const v8bf*)&Vt[n * 16 + l16][ks * 32 + kg * 8];
      acc[n] = __builtin_amdgcn_mfma_f32_16x16x32_bf16(a, bv, acc[n], 0, 0, 0);
    }
  }
#pragma unroll
  for (int n = 0; n < 4; ++n)
#pragma unroll
    for (int v = 0; v < 4; ++v) {
      const int o = w * 16 + kg * 4 + v;
      out[(((size_t)b * 64 + o) * 512 + q) * 64 + n * 16 + l16] = acc[n][v] + bias[o];
    }
}

extern "C" void kernel_launch(void* const* d_in, const int* in_sizes, int n_in,
                              void* d_out, int out_size, void* d_ws, size_t ws_size,
                              hipStream_t stream) {
  const float* x   = (const float*)d_in[0];  // [16,512,32,64]
  const float* adj = (const float*)d_in[1];  // [16,512,512]
  const float* W   = (const float*)d_in[2];  // [64,96]
  const float* bia = (const float*)d_in[3];  // [64]
  float* out = (float*)d_out;                // [16,64,512,64]

  u16* adjC    = (u16*)d_ws;                              // [16][1024][512]
  u16* adjT_bf = adjC    + (size_t)16 * 1024 * 512;       // [16][512][512]
  u16* xT      = adjT_bf + (size_t)16 * 512 * 512;        // [16][2048][512]
  u16* X1Y2    = xT      + (size_t)16 * 2048 * 512;       // [16][1024][2048]
  u16* Mb      = X1Y2    + (size_t)16 * 1024 * 2048;

  hipLaunchKernelGGL(prep_k, dim3(5121), dim3(256), 0, stream,
                     adj, adjC, adjT_bf, x, xT, W, Mb);
  hipLaunchKernelGGL(gemm_sq, dim3(4, 4, 16), dim3(256), 0, stream,
                     adjC, adjT_bf, adjC);
  hipLaunchKernelGGL(prop_k, dim3(16, 8, 16), dim3(256), 0, stream,
                     adjC, xT, X1Y2);
  hipLaunchKernelGGL(mix_mfma, dim3(512, 16), dim3(256), 0, stream,
                     x, X1Y2, Mb, bia, out);
}

// Round 17
// 133.747 us; speedup vs baseline: 1.1140x; 1.0354x over previous
//
#include <hip/hip_runtime.h>

typedef unsigned short u16;
typedef __bf16 v8bf __attribute__((ext_vector_type(8)));
typedef float f32x4 __attribute__((ext_vector_type(4)));
typedef float f32x16 __attribute__((ext_vector_type(16)));
typedef u16 us8 __attribute__((ext_vector_type(8)));
typedef u16 us4 __attribute__((ext_vector_type(4)));

static __device__ __forceinline__ u16 f2bf(float f) {
  union { __bf16 h; u16 u; } cv;
  cv.h = (__bf16)f;
  return cv.u;
}

static __device__ __forceinline__ void gl_lds16(const u16* g, u16* l) {
  __builtin_amdgcn_global_load_lds(
      (const __attribute__((address_space(1))) unsigned int*)g,
      (__attribute__((address_space(3))) unsigned int*)l, 16, 0, 0);
}

// ---- prep_adj (R15-proven): adj->adjC top half (+adjT) [blocks 0..1023],
//      foldW [1024]. ----
__global__ __launch_bounds__(256)
void prep_adj_k(const float* __restrict__ adj, u16* __restrict__ adjC,
                u16* __restrict__ adjT_bf, const float* __restrict__ W,
                u16* __restrict__ Mb) {
  const int bid = blockIdx.x;
  const int tid = threadIdx.x;
  __shared__ u16 Ls[64][68];
  if (bid < 1024) {
    const int b = bid >> 6;
    const int r0 = ((bid >> 3) & 7) * 64;
    const int c0 = (bid & 7) * 64;
#pragma unroll
    for (int i = 0; i < 4; ++i) {
      const int idx = tid + 256 * i;
      const int r = idx >> 4;
      const int c4 = (idx & 15) * 4;
      const float4 v = *(const float4*)(adj + ((size_t)(b * 512 + r0 + r) * 512 + c0 + c4));
      us4 o;
      o[0] = f2bf(v.x); o[1] = f2bf(v.y); o[2] = f2bf(v.z); o[3] = f2bf(v.w);
      *(us4*)&Ls[r][c4] = o;
      *(us4*)(adjC + ((size_t)(b * 1024 + r0 + r) * 512 + c0 + c4)) = o;
    }
    __syncthreads();
#pragma unroll
    for (int i = 0; i < 2; ++i) {
      const int idx = tid + 256 * i;
      const int c = idx >> 3;
      const int r8 = (idx & 7) * 8;
      us8 o;
#pragma unroll
      for (int j = 0; j < 8; ++j) o[j] = Ls[r8 + j][c];
      *(us8*)(adjT_bf + ((size_t)(b * 512 + c0 + c) * 512 + r0 + r8)) = o;
    }
  } else {
    for (int i = tid; i < 64 * 96; i += 256) {
      const int cc = i % 96;
      const int r = cc % 3;
      const float w = W[i];
      const float m = (r == 0) ? (w - W[i + 2]) : w;
      Mb[i] = f2bf(m);
    }
  }
}

// ---- phase2: blocks 0..255 = gemm_sq (adjC lower = 2*adj@adj, R13 body);
//      blocks 256..4351 = x->xT transpose (R13 prep x-branch body).
//      Independent work items -> concurrent: MFMA hides under memory pass. ----
__global__ __launch_bounds__(256)
void phase2_k(const u16* __restrict__ adjC_in, const u16* __restrict__ BT,
              u16* __restrict__ adjC, const float* __restrict__ x,
              u16* __restrict__ xT) {
  const int bid = blockIdx.x;
  const int tid = threadIdx.x;
  __shared__ u16 smem[16384];
  if (bid < 256) {
    // gemm_sq body (R13-proven), flat bid remap
    const int b = bid >> 4;
    const int row0 = ((bid >> 2) & 3) * 128;
    const int col0 = (bid & 3) * 128;
    const u16* Ab = adjC_in + (size_t)b * 1024 * 512;
    const u16* BTb = BT + (size_t)b * 512 * 512;

    u16* As = smem;
    u16* Bs = smem + 8192;

    const int lane = tid & 63;
    const int w = tid >> 6;
    const int wm = (w >> 1) * 64;
    const int wn = (w & 1) * 64;
    const int l16 = lane & 15;
    const int kg = lane >> 4;

    f32x4 acc[4][4];
#pragma unroll
    for (int m = 0; m < 4; ++m)
#pragma unroll
      for (int n = 0; n < 4; ++n) acc[m][n] = (f32x4){0.f, 0.f, 0.f, 0.f};

    for (int k0 = 0; k0 < 512; k0 += 64) {
      __syncthreads();
#pragma unroll
      for (int i = 0; i < 4; ++i) {
        const int eb = w * 2048 + i * 512;
        const int e = eb + lane * 8;
        const int r = e >> 6;
        const int kk = e & 63;
        gl_lds16(Ab + (size_t)(row0 + r) * 512 + k0 + kk, As + eb);
        gl_lds16(BTb + (size_t)(col0 + r) * 512 + k0 + kk, Bs + eb);
      }
      __syncthreads();
#pragma unroll
      for (int ks = 0; ks < 2; ++ks) {
        v8bf af[4], bfr[4];
#pragma unroll
        for (int m = 0; m < 4; ++m)
          af[m] = *(const v8bf*)(As + (wm + m * 16 + l16) * 64 + ks * 32 + kg * 8);
#pragma unroll
        for (int n = 0; n < 4; ++n)
          bfr[n] = *(const v8bf*)(Bs + (wn + n * 16 + l16) * 64 + ks * 32 + kg * 8);
#pragma unroll
        for (int m = 0; m < 4; ++m)
#pragma unroll
          for (int n = 0; n < 4; ++n)
            acc[m][n] = __builtin_amdgcn_mfma_f32_16x16x32_bf16(af[m], bfr[n], acc[m][n], 0, 0, 0);
      }
    }
    u16* Cb = adjC + (size_t)b * 1024 * 512 + (size_t)512 * 512;
#pragma unroll
    for (int m = 0; m < 4; ++m)
#pragma unroll
      for (int n = 0; n < 4; ++n)
#pragma unroll
        for (int v = 0; v < 4; ++v) {
          const int rr = row0 + wm + m * 16 + kg * 4 + v;
          const int cc = col0 + wn + n * 16 + l16;
          Cb[(size_t)rr * 512 + cc] = f2bf(2.0f * acc[m][n][v]);
        }
  } else {
    // x -> xT transpose body (R13-proven)
    u16 (*Ls)[68] = (u16(*)[68])smem;
    const int t = bid - 256;
    const int b = t >> 8;
    const int q0 = ((t >> 5) & 7) * 64;
    const int j0 = (t & 31) * 64;
#pragma unroll
    for (int i = 0; i < 4; ++i) {
      const int idx = tid + 256 * i;
      const int r = idx >> 4;
      const int j4 = (idx & 15) * 4;
      const float4 v = *(const float4*)(x + ((size_t)(b * 512 + q0 + r) * 2048 + j0 + j4));
      us4 o;
      o[0] = f2bf(v.x); o[1] = f2bf(v.y); o[2] = f2bf(v.z); o[3] = f2bf(v.w);
      *(us4*)&Ls[r][j4] = o;
    }
    __syncthreads();
#pragma unroll
    for (int i = 0; i < 2; ++i) {
      const int idx = tid + 256 * i;
      const int jp = idx >> 3;
      const int q8 = (idx & 7) * 8;
      us8 o;
#pragma unroll
      for (int j = 0; j < 8; ++j) o[j] = Ls[q8 + j][jp];
      *(us8*)(xT + ((size_t)(b * 2048 + j0 + jp) * 512 + q0 + q8)) = o;
    }
  }
}

// ---- propagate (R13-proven best): 256x128 tile, 8 waves, 32x32x16 MFMA,
//      XOR-swizzled LDS both-sides. X1Y2[b](1024x2048) = adjC[b] @ X[b]. ----
__global__ __launch_bounds__(512)
void prop_k(const u16* __restrict__ AC, const u16* __restrict__ BT,
            u16* __restrict__ C) {
  const int fid = blockIdx.x + 16 * (blockIdx.y + 4 * blockIdx.z);
  const int wk = (fid & 7) * 128 + (fid >> 3);   // bijective: 1024 % 8 == 0
  const int b = wk >> 6;
  const int row0 = ((wk >> 4) & 3) * 256;
  const int col0 = (wk & 15) * 128;
  const u16* Ab = AC + (size_t)b * 1024 * 512;
  const u16* BTb = BT + (size_t)b * 2048 * 512;

  __shared__ u16 smem[24576];  // A [256][64] = 32KB, B [128][64] = 16KB
  u16* As = smem;
  u16* Bs = smem + 16384;

  const int tid = threadIdx.x;
  const int lane = tid & 63;
  const int w = tid >> 6;
  const int wm = (w >> 1) * 64;
  const int wn = (w & 1) * 64;
  const int l32 = lane & 31;
  const int hk = lane >> 5;
  const int rsw = (l32 & 7) << 3;

  f32x16 acc[2][2];
#pragma unroll
  for (int mi = 0; mi < 2; ++mi)
#pragma unroll
    for (int ni = 0; ni < 2; ++ni)
#pragma unroll
      for (int v = 0; v < 16; ++v) acc[mi][ni][v] = 0.f;

  for (int k0 = 0; k0 < 512; k0 += 64) {
    __syncthreads();
#pragma unroll
    for (int i = 0; i < 4; ++i) {
      const int cb = w * 64 + i * 512;
      const int c = cb + lane;
      const int r = c >> 3;
      const int slot = (c & 7) ^ (r & 7);
      gl_lds16(Ab + (size_t)(row0 + r) * 512 + k0 + slot * 8, As + cb * 8);
    }
#pragma unroll
    for (int i = 0; i < 2; ++i) {
      const int cb = w * 64 + i * 512;
      const int c = cb + lane;
      const int r = c >> 3;
      const int slot = (c & 7) ^ (r & 7);
      gl_lds16(BTb + (size_t)(col0 + r) * 512 + k0 + slot * 8, Bs + cb * 8);
    }
    __syncthreads();
#pragma unroll
    for (int ks = 0; ks < 4; ++ks) {
      v8bf af[2], bf[2];
#pragma unroll
      for (int mi = 0; mi < 2; ++mi) {
        const int row = wm + mi * 32 + l32;
        af[mi] = *(const v8bf*)(As + row * 64 + ((ks * 16 + hk * 8) ^ rsw));
      }
#pragma unroll
      for (int ni = 0; ni < 2; ++ni) {
        const int row = wn + ni * 32 + l32;
        bf[ni] = *(const v8bf*)(Bs + row * 64 + ((ks * 16 + hk * 8) ^ rsw));
      }
#pragma unroll
      for (int mi = 0; mi < 2; ++mi)
#pragma unroll
        for (int ni = 0; ni < 2; ++ni)
          acc[mi][ni] = __builtin_amdgcn_mfma_f32_32x32x16_bf16(af[mi], bf[ni], acc[mi][ni], 0, 0, 0);
    }
  }

  u16* Cb = C + (size_t)b * 1024 * 2048;
#pragma unroll
  for (int mi = 0; mi < 2; ++mi)
#pragma unroll
    for (int ni = 0; ni < 2; ++ni)
#pragma unroll
      for (int r = 0; r < 16; ++r) {
        const int rr = row0 + wm + mi * 32 + (r & 3) + 8 * (r >> 2) + 4 * hk;
        const int cc = col0 + wn + ni * 32 + l32;
        Cb[(size_t)rr * 2048 + cc] = f2bf(acc[mi][ni][r]);
      }
}

// ---- mix (R13-proven, unchanged) ----
__global__ __launch_bounds__(256)
void mix_mfma(const float* __restrict__ x0, const u16* __restrict__ X1Y2,
              const u16* __restrict__ Mb, const float* __restrict__ bias,
              float* __restrict__ out) {
  const int q = blockIdx.x;
  const int b = blockIdx.y;
  __shared__ u16 Vt[64][104];
  __shared__ u16 Ms[64][104];
  const int tid = threadIdx.x;
  const int lane = tid & 63;
  const int w = tid >> 6;
  const int l16 = lane & 15;
  const int kg = lane >> 4;

#pragma unroll
  for (int i = 0; i < 3; ++i) {
    const int idx = tid + 256 * i;
    const int o = idx / 12;
    const int c8 = (idx % 12) * 8;
    *(uint4*)&Ms[o][c8] = *(const uint4*)(Mb + o * 96 + c8);
  }
  const size_t base0 = ((size_t)b * 512 + q) * 2048;
  const size_t base1 = ((size_t)b * 1024 + q) * 2048;
  const size_t base2 = ((size_t)b * 1024 + 512 + q) * 2048;
#pragma unroll
  for (int i = 0; i < 2; ++i) {
    const int idx = tid + 256 * i;
    const int c = idx >> 4;
    const int l0 = (idx & 15) * 4;
    const float4 v = *(const float4*)(x0 + base0 + c * 64 + l0);
    Vt[l0 + 0][3 * c] = f2bf(v.x);
    Vt[l0 + 1][3 * c] = f2bf(v.y);
    Vt[l0 + 2][3 * c] = f2bf(v.z);
    Vt[l0 + 3][3 * c] = f2bf(v.w);
  }
  {
    const int c = tid >> 3;
    const int l0 = (tid & 7) * 8;
    const us8 v1 = *(const us8*)(X1Y2 + base1 + c * 64 + l0);
    const us8 v2 = *(const us8*)(X1Y2 + base2 + c * 64 + l0);
#pragma unroll
    for (int j = 0; j < 8; ++j) {
      Vt[l0 + j][3 * c + 1] = v1[j];
      Vt[l0 + j][3 * c + 2] = v2[j];
    }
  }
  __syncthreads();

  f32x4 acc[4];
#pragma unroll
  for (int n = 0; n < 4; ++n) acc[n] = (f32x4){0.f, 0.f, 0.f, 0.f};
#pragma unroll
  for (int ks = 0; ks < 3; ++ks) {
    const v8bf a = *(const v8bf*)&Ms[w * 16 + l16][ks * 32 + kg * 8];
#pragma unroll
    for (int n = 0; n < 4; ++n) {
      const v8bf bv = *(const v8bf*)&Vt[n * 16 + l16][ks * 32 + kg * 8];
      acc[n] = __builtin_amdgcn_mfma_f32_16x16x32_bf16(a, bv, acc[n], 0, 0, 0);
    }
  }
#pragma unroll
  for (int n = 0; n < 4; ++n)
#pragma unroll
    for (int v = 0; v < 4; ++v) {
      const int o = w * 16 + kg * 4 + v;
      out[(((size_t)b * 64 + o) * 512 + q) * 64 + n * 16 + l16] = acc[n][v] + bias[o];
    }
}

extern "C" void kernel_launch(void* const* d_in, const int* in_sizes, int n_in,
                              void* d_out, int out_size, void* d_ws, size_t ws_size,
                              hipStream_t stream) {
  const float* x   = (const float*)d_in[0];  // [16,512,32,64]
  const float* adj = (const float*)d_in[1];  // [16,512,512]
  const float* W   = (const float*)d_in[2];  // [64,96]
  const float* bia = (const float*)d_in[3];  // [64]
  float* out = (float*)d_out;                // [16,64,512,64]

  u16* adjC    = (u16*)d_ws;                              // [16][1024][512]
  u16* adjT_bf = adjC    + (size_t)16 * 1024 * 512;       // [16][512][512]
  u16* xT      = adjT_bf + (size_t)16 * 512 * 512;        // [16][2048][512]
  u16* X1Y2    = xT      + (size_t)16 * 2048 * 512;       // [16][1024][2048]
  u16* Mb      = X1Y2    + (size_t)16 * 1024 * 2048;

  hipLaunchKernelGGL(prep_adj_k, dim3(1025), dim3(256), 0, stream,
                     adj, adjC, adjT_bf, W, Mb);
  hipLaunchKernelGGL(phase2_k, dim3(4352), dim3(256), 0, stream,
                     adjC, adjT_bf, adjC, x, xT);
  hipLaunchKernelGGL(prop_k, dim3(16, 4, 16), dim3(512), 0, stream,
                     adjC, xT, X1Y2);
  hipLaunchKernelGGL(mix_mfma, dim3(512, 16), dim3(256), 0, stream,
                     x, X1Y2, Mb, bia, out);
}